// Round 12
// baseline (2443.356 us; speedup 1.0000x reference)
//
#include <hip/hip_runtime.h>

// Scatter-mean graph propagation, 8 rounds (4 fwd + 4 rev).
//
// ROUND-12: e_pass is divergent-gather ADDRESS-RATE bound (~1 lane/cy/CU
// => ~104us floor per 64M-edge pass) and ran at only 42-68% occupancy
// (245-489 blocks x 1024 thr = ~16 waves/CU). r11's src-sorting proved
// locality/BW/conflicts irrelevant (199 vs 190us). Fix: fuse the two
// INDEPENDENT direction-chains into one dispatch per round:
//   - partition BOTH directions up front (packed_f + packed_r, ~522MB ws)
//   - e_pass_dual: grid = 2*NB blocks of 512 threads (8-16KB LDS/block ->
//     ~4 blocks/CU, ~95% occupancy); block handles (dir, bucket).
// Inner loop = r5/r10 proven scalar gather + LDS atomic + fused normalize
// (reciprocal counts built in round 1).
//
// MID PATH (ws holds one packed array): sequential directions (r10, 1742us).
// FALLBACK: global-atomic version.

typedef unsigned uint32x4 __attribute__((ext_vector_type(4)));

#define TPB_E 512
#define NPART 512
#define TPB_P 512
#define BATCH 8192
#define CAP 32
#define NBMAX 512      // max buckets (N <= 2^20 -> NB <= 512)
#define BSH 11         // bucket shift
#define BSZ 2048       // nodes per bucket
#define BMASK 2047u

// ---------------- partition machinery (r5/r10 proven) ----------------

__global__ __launch_bounds__(TPB_P)
void p1_count(const int* __restrict__ dst, unsigned* __restrict__ blkcnt,
              int E, int chunk, int NB) {
    __shared__ unsigned h[NBMAX];
    for (int i = threadIdx.x; i < NB; i += TPB_P) h[i] = 0u;
    __syncthreads();
    int beg = blockIdx.x * chunk;
    int end = min(beg + chunk, E);
    int len = end - beg; if (len < 0) len = 0;
    const uint32x4* d4 = (const uint32x4*)(dst + beg);   // beg multiple of 16
    int n4 = len >> 2;
    for (int i = threadIdx.x; i < n4; i += TPB_P) {
        uint32x4 d = __builtin_nontemporal_load(&d4[i]);
        atomicAdd(&h[d.x >> BSH], 1u);
        atomicAdd(&h[d.y >> BSH], 1u);
        atomicAdd(&h[d.z >> BSH], 1u);
        atomicAdd(&h[d.w >> BSH], 1u);
    }
    __syncthreads();
    unsigned* o = blkcnt + (size_t)blockIdx.x * NB;
    for (int i = threadIdx.x; i < NB; i += TPB_P) o[i] = h[i];
}

__global__ __launch_bounds__(TPB_P)
void s1_totals(const unsigned* __restrict__ blkcnt, unsigned* __restrict__ totals,
               int NB, int nblk) {
    __shared__ unsigned red[TPB_P];
    int b = blockIdx.x;
    unsigned s = 0;
    for (int k = threadIdx.x; k < nblk; k += TPB_P) s += blkcnt[(size_t)k * NB + b];
    red[threadIdx.x] = s;
    __syncthreads();
    for (int off = TPB_P / 2; off > 0; off >>= 1) {
        if (threadIdx.x < off) red[threadIdx.x] += red[threadIdx.x + off];
        __syncthreads();
    }
    if (threadIdx.x == 0) totals[b] = red[0];
}

__global__ __launch_bounds__(TPB_P)
void s2_scan(const unsigned* __restrict__ totals, unsigned* __restrict__ base, int NB) {
    __shared__ unsigned t[TPB_P];
    int tid = threadIdx.x;
    unsigned v = (tid < NB) ? totals[tid] : 0u;
    t[tid] = v;
    __syncthreads();
    for (int off = 1; off < TPB_P; off <<= 1) {
        unsigned w = (tid >= off) ? t[tid - off] : 0u;
        __syncthreads();
        t[tid] += w;
        __syncthreads();
    }
    if (tid < NB) base[tid] = t[tid] - v;
    if (tid == NB - 1) base[NB] = t[tid];
}

__global__ __launch_bounds__(TPB_P)
void s3_start(const unsigned* __restrict__ blkcnt, const unsigned* __restrict__ base,
              unsigned* __restrict__ start, int NB, int nblk) {
    __shared__ unsigned t[TPB_P];
    int b = blockIdx.x;
    int tid = threadIdx.x;
    unsigned v = (tid < nblk) ? blkcnt[(size_t)tid * NB + b] : 0u;
    t[tid] = v;
    __syncthreads();
    for (int off = 1; off < TPB_P; off <<= 1) {
        unsigned w = (tid >= off) ? t[tid - off] : 0u;
        __syncthreads();
        t[tid] += w;
        __syncthreads();
    }
    if (tid < nblk) start[(size_t)tid * NB + b] = base[b] + t[tid] - v;
}

__global__ __launch_bounds__(TPB_P)
void p2_scatter(const int* __restrict__ src, const int* __restrict__ dst,
                const unsigned* __restrict__ start, unsigned* __restrict__ packed,
                int E, int chunk, int NB) {
    __shared__ unsigned stg[NBMAX * CAP];   // 64 KB staging
    __shared__ unsigned h[NBMAX];
    __shared__ unsigned gcur[NBMAX];
    int tid = threadIdx.x;
    int bid = blockIdx.x;
    for (int i = tid; i < NB; i += TPB_P) gcur[i] = start[(size_t)bid * NB + i];
    int beg = bid * chunk;
    int end = min(beg + chunk, E);
    int wid = tid >> 6, lane = tid & 63;
    for (int bb = beg; bb < end; bb += BATCH) {
        int bend = min(bb + BATCH, end);
        int n4 = (bend - bb) >> 2;          // batch multiple of 16
        for (int i = tid; i < NB; i += TPB_P) h[i] = 0u;
        __syncthreads();
        const uint32x4* s4 = (const uint32x4*)(src + bb);
        const uint32x4* d4 = (const uint32x4*)(dst + bb);
        for (int i = tid; i < n4; i += TPB_P) {
            uint32x4 s = __builtin_nontemporal_load(&s4[i]);
            uint32x4 d = __builtin_nontemporal_load(&d4[i]);
            unsigned sv[4] = {s.x, s.y, s.z, s.w};
            unsigned dv[4] = {d.x, d.y, d.z, d.w};
            #pragma unroll
            for (int k = 0; k < 4; ++k) {
                unsigned b = dv[k] >> BSH;
                unsigned val = (sv[k] << BSH) | (dv[k] & BMASK);
                unsigned pos = atomicAdd(&h[b], 1u);
                if (pos < CAP) stg[(b << 5) + ((pos + b) & 31u)] = val;  // bank-rotated
                else packed[gcur[b] + pos] = val;   // rare overflow
            }
        }
        __syncthreads();
        for (int b = wid; b < NB; b += TPB_P / 64) {
            unsigned cnt = h[b];
            unsigned n = cnt < CAP ? cnt : CAP;
            unsigned g0 = gcur[b];
            for (unsigned i = lane; i < n; i += 64)
                packed[g0 + i] = stg[(b << 5) + ((i + b) & 31u)];
            if (lane == 0) gcur[b] = g0 + cnt;
        }
        __syncthreads();
    }
}

// ---------------- e_pass_dual: both directions in one dispatch ----------------
// grid.x = 2*NB (or NB for single-direction use); block b<NB -> fwd bucket b,
// b>=NB -> rev bucket b-NB. 512 threads, 8-16KB LDS -> ~4 blocks/CU.

template <bool FIRST>
__global__ __launch_bounds__(TPB_E)
void e_pass_dual(const float* __restrict__ xf, const float* __restrict__ xr,
                 const unsigned* __restrict__ pf, const unsigned* __restrict__ pr,
                 const unsigned* __restrict__ basef, const unsigned* __restrict__ baser,
                 float* __restrict__ rcntf, float* __restrict__ rcntr,
                 float* __restrict__ outf, float* __restrict__ outr,
                 int N, int NB) {
    __shared__ float acc[BSZ];
    __shared__ unsigned c[FIRST ? BSZ : 1];
    int tid = threadIdx.x;
    for (int i = tid; i < BSZ; i += TPB_E) {
        acc[i] = 0.0f;
        if (FIRST) c[i] = 0u;
    }
    __syncthreads();
    int b = blockIdx.x;
    bool rev = (b >= NB);
    int bb = rev ? b - NB : b;
    const float* x = rev ? xr : xf;
    const unsigned* packed = rev ? pr : pf;
    const unsigned* boff = rev ? baser : basef;
    float* rcnt = rev ? rcntr : rcntf;
    float* outslice = rev ? outr : outf;

    int beg = (int)boff[bb], end = (int)boff[bb + 1];
    for (int e = beg + tid; e < end; e += TPB_E) {
        unsigned p = __builtin_nontemporal_load(&packed[e]);
        atomicAdd(&acc[p & BMASK], x[p >> BSH]);
        if (FIRST) atomicAdd(&c[p & BMASK], 1u);
    }
    __syncthreads();
    int nbase = bb << BSH;
    for (int i = tid; i < BSZ; i += TPB_E) {
        int node = nbase + i;
        if (node < N) {
            float rc;
            if (FIRST) {
                unsigned cv = c[i];
                rc = 1.0f / (float)(cv > 0u ? cv : 1u);
                rcnt[node] = rc;
            } else {
                rc = rcnt[node];
            }
            outslice[node] = acc[i] * rc;
        }
    }
}

// ---------------- fallback (global atomics) ----------------

#define TPB 256
#define MAX_BLOCKS 2048

__global__ void round_first(const float* __restrict__ x, const int* __restrict__ src,
                            const int* __restrict__ dst, float* __restrict__ agg,
                            float* __restrict__ cnt, int nE) {
    int i = blockIdx.x * blockDim.x + threadIdx.x;
    int stride = gridDim.x * blockDim.x;
    for (; i < nE; i += stride) {
        atomicAdd(&agg[dst[i]], x[src[i]]);
        atomicAdd(&cnt[dst[i]], 1.0f);
    }
}

__global__ void round_next(const float* __restrict__ x, const int* __restrict__ src,
                           const int* __restrict__ dst, float* __restrict__ agg, int nE) {
    int i = blockIdx.x * blockDim.x + threadIdx.x;
    int stride = gridDim.x * blockDim.x;
    for (; i < nE; i += stride) atomicAdd(&agg[dst[i]], x[src[i]]);
}

__global__ void normalize_k(float* __restrict__ out, const float* __restrict__ cnt, int n) {
    int i = blockIdx.x * blockDim.x + threadIdx.x;
    int stride = gridDim.x * blockDim.x;
    for (; i < n; i += stride) out[i] /= fmaxf(cnt[i], 1.0f);
}

// ---------------- launch ----------------

extern "C" void kernel_launch(void* const* d_in, const int* in_sizes, int n_in,
                              void* d_out, int out_size, void* d_ws, size_t ws_size,
                              hipStream_t stream) {
    const float* topic = (const float*)d_in[0];
    const int* ei  = (const int*)d_in[1];
    const int* rei = (const int*)d_in[2];
    const int N = in_sizes[0];
    const int E = in_sizes[1] / 2;

    float* out = (float*)d_out;   // 8 slices of N floats

    const int NB = (N + BSZ - 1) >> BSH;
    const int chunk = ((E + NPART * 16 - 1) / (NPART * 16)) * 16;

    size_t off = 0;
    auto alloc = [&](size_t bytes) { size_t o = off; off += (bytes + 255) & ~(size_t)255; return o; };
    size_t o_packed_f = alloc((size_t)E * 4);
    size_t o_rcnt_f   = alloc((size_t)N * 4);
    size_t o_rcnt_r   = alloc((size_t)N * 4);
    size_t o_blkcnt   = alloc((size_t)NPART * NB * 4);
    size_t o_start    = alloc((size_t)NPART * NB * 4);
    size_t o_totals   = alloc((size_t)NBMAX * 4);
    size_t o_base_f   = alloc((size_t)(NBMAX + 1) * 4);
    size_t o_base_r   = alloc((size_t)(NBMAX + 1) * 4);
    size_t need_seq   = off;
    size_t o_packed_r = alloc((size_t)E * 4);
    size_t need_dual  = off;

    bool shapes_ok = (NB >= 2) && (NB <= NBMAX) && (N <= (1 << 20)) &&
                     (E % 16 == 0) && (E > 0);
    bool dual = shapes_ok && (need_dual <= ws_size);
    bool seq  = shapes_ok && (need_seq <= ws_size);

    if (dual || seq) {
        char* ws = (char*)d_ws;
        unsigned* packed_f = (unsigned*)(ws + o_packed_f);
        unsigned* packed_r = dual ? (unsigned*)(ws + o_packed_r) : nullptr;
        float*    rcnt_f   = (float*)(ws + o_rcnt_f);
        float*    rcnt_r   = (float*)(ws + o_rcnt_r);
        unsigned* blkcnt   = (unsigned*)(ws + o_blkcnt);
        unsigned* start    = (unsigned*)(ws + o_start);
        unsigned* totals   = (unsigned*)(ws + o_totals);
        unsigned* base_f   = (unsigned*)(ws + o_base_f);
        unsigned* base_r   = (unsigned*)(ws + o_base_r);

        if (dual) {
            // partition both directions up front
            for (int dir = 0; dir < 2; ++dir) {
                const int* src = (dir == 0) ? ei : rei;
                const int* dst = src + E;
                unsigned* packed = (dir == 0) ? packed_f : packed_r;
                unsigned* base   = (dir == 0) ? base_f : base_r;
                p1_count<<<NPART, TPB_P, 0, stream>>>(dst, blkcnt, E, chunk, NB);
                s1_totals<<<NB, TPB_P, 0, stream>>>(blkcnt, totals, NB, NPART);
                s2_scan<<<1, TPB_P, 0, stream>>>(totals, base, NB);
                s3_start<<<NB, TPB_P, 0, stream>>>(blkcnt, base, start, NB, NPART);
                p2_scatter<<<NPART, TPB_P, 0, stream>>>(src, dst, start, packed, E, chunk, NB);
            }
            // fused rounds: one dispatch covers both directions
            float* out_f = out;                      // slices 0..3
            float* out_r = out + (size_t)4 * N;      // slices 4..7
            e_pass_dual<true><<<2 * NB, TPB_E, 0, stream>>>(
                topic, topic, packed_f, packed_r, base_f, base_r,
                rcnt_f, rcnt_r, out_f, out_r, N, NB);
            for (int r = 1; r < 4; ++r) {
                e_pass_dual<false><<<2 * NB, TPB_E, 0, stream>>>(
                    out_f + (size_t)(r - 1) * N, out_r + (size_t)(r - 1) * N,
                    packed_f, packed_r, base_f, base_r,
                    rcnt_f, rcnt_r,
                    out_f + (size_t)r * N, out_r + (size_t)r * N, N, NB);
            }
        } else {
            // sequential directions sharing one packed buffer (r10-equivalent)
            for (int dir = 0; dir < 2; ++dir) {
                const int* src = (dir == 0) ? ei : rei;
                const int* dst = src + E;
                float* oslab = out + (size_t)dir * 4 * N;
                float* rcnt  = (dir == 0) ? rcnt_f : rcnt_r;
                unsigned* base = (dir == 0) ? base_f : base_r;
                p1_count<<<NPART, TPB_P, 0, stream>>>(dst, blkcnt, E, chunk, NB);
                s1_totals<<<NB, TPB_P, 0, stream>>>(blkcnt, totals, NB, NPART);
                s2_scan<<<1, TPB_P, 0, stream>>>(totals, base, NB);
                s3_start<<<NB, TPB_P, 0, stream>>>(blkcnt, base, start, NB, NPART);
                p2_scatter<<<NPART, TPB_P, 0, stream>>>(src, dst, start, packed_f, E, chunk, NB);
                e_pass_dual<true><<<NB, TPB_E, 0, stream>>>(
                    topic, topic, packed_f, packed_f, base, base,
                    rcnt, rcnt, oslab, oslab, N, NB);
                for (int r = 1; r < 4; ++r) {
                    e_pass_dual<false><<<NB, TPB_E, 0, stream>>>(
                        oslab + (size_t)(r - 1) * N, oslab + (size_t)(r - 1) * N,
                        packed_f, packed_f, base, base, rcnt, rcnt,
                        oslab + (size_t)r * N, oslab + (size_t)r * N, N, NB);
                }
            }
        }
        return;
    }

    // -------- fallback: global-atomic version --------
    const int* src = ei;
    const int* dst = ei + E;
    const int* rsrc = rei;
    const int* rdst = rei + E;

    float* cnt_f = (float*)d_ws;
    float* cnt_r = cnt_f + N;

    (void)hipMemsetAsync(d_out, 0, (size_t)out_size * sizeof(float), stream);
    (void)hipMemsetAsync(d_ws, 0, (size_t)2 * N * sizeof(float), stream);

    int eb = (E + TPB - 1) / TPB; if (eb > MAX_BLOCKS) eb = MAX_BLOCKS;
    int nb = (N + TPB - 1) / TPB; if (nb > MAX_BLOCKS) nb = MAX_BLOCKS;

    round_first<<<eb, TPB, 0, stream>>>(topic, src, dst, out, cnt_f, E);
    normalize_k<<<nb, TPB, 0, stream>>>(out, cnt_f, N);
    for (int r = 1; r < 4; ++r) {
        round_next<<<eb, TPB, 0, stream>>>(out + (size_t)(r - 1) * N, src, dst,
                                           out + (size_t)r * N, E);
        normalize_k<<<nb, TPB, 0, stream>>>(out + (size_t)r * N, cnt_f, N);
    }
    round_first<<<eb, TPB, 0, stream>>>(topic, rsrc, rdst, out + (size_t)4 * N, cnt_r, E);
    normalize_k<<<nb, TPB, 0, stream>>>(out + (size_t)4 * N, cnt_r, N);
    for (int r = 5; r < 8; ++r) {
        round_next<<<eb, TPB, 0, stream>>>(out + (size_t)(r - 1) * N, rsrc, rdst,
                                           out + (size_t)r * N, E);
        normalize_k<<<nb, TPB, 0, stream>>>(out + (size_t)r * N, cnt_r, N);
    }
}

// Round 13
// 1959.490 us; speedup vs baseline: 1.2469x; 1.2469x over previous
//
#include <hip/hip_runtime.h>

// Scatter-mean graph propagation, 8 rounds (4 fwd + 4 rev).
//
// ROUND-13: r12's dual fusion raised occupancy (82%) but thrashed per-XCD L2
// (2 x-arrays = 8MB > 4MB L2 -> gathers fell to L3: FETCH 101MB->2GB, 576us).
// Fix: XCD-aware block mapping. blockIdx round-robins XCDs by (id % 8);
// map slots with (s&7)<4 -> forward buckets, (s&7)>=4 -> reverse buckets.
// Each XCD then gathers from ONE 4MB x array (L2-resident, r10-proven) while
// the fused grid keeps ~95% occupancy (984 blocks x 512 thr).
//   - partition both directions up front (r5-proven staged scatter)
//   - 4 fused rounds: e_pass_dual<.,true> with the swizzled mapping
// Inner loop unchanged (r5/r10 proven): nt packed read, gather, LDS atomic,
// fused normalize with reciprocal counts.
//
// MID PATH (ws holds one packed array): sequential directions (r10, 1742us).
// FALLBACK: global-atomic version.

typedef unsigned uint32x4 __attribute__((ext_vector_type(4)));

#define TPB_E 512
#define NPART 512
#define TPB_P 512
#define BATCH 8192
#define CAP 32
#define NBMAX 512      // max buckets (N <= 2^20 -> NB <= 512)
#define BSH 11         // bucket shift
#define BSZ 2048       // nodes per bucket
#define BMASK 2047u

// ---------------- partition machinery (r5/r10 proven) ----------------

__global__ __launch_bounds__(TPB_P)
void p1_count(const int* __restrict__ dst, unsigned* __restrict__ blkcnt,
              int E, int chunk, int NB) {
    __shared__ unsigned h[NBMAX];
    for (int i = threadIdx.x; i < NB; i += TPB_P) h[i] = 0u;
    __syncthreads();
    int beg = blockIdx.x * chunk;
    int end = min(beg + chunk, E);
    int len = end - beg; if (len < 0) len = 0;
    const uint32x4* d4 = (const uint32x4*)(dst + beg);   // beg multiple of 16
    int n4 = len >> 2;
    for (int i = threadIdx.x; i < n4; i += TPB_P) {
        uint32x4 d = __builtin_nontemporal_load(&d4[i]);
        atomicAdd(&h[d.x >> BSH], 1u);
        atomicAdd(&h[d.y >> BSH], 1u);
        atomicAdd(&h[d.z >> BSH], 1u);
        atomicAdd(&h[d.w >> BSH], 1u);
    }
    __syncthreads();
    unsigned* o = blkcnt + (size_t)blockIdx.x * NB;
    for (int i = threadIdx.x; i < NB; i += TPB_P) o[i] = h[i];
}

__global__ __launch_bounds__(TPB_P)
void s1_totals(const unsigned* __restrict__ blkcnt, unsigned* __restrict__ totals,
               int NB, int nblk) {
    __shared__ unsigned red[TPB_P];
    int b = blockIdx.x;
    unsigned s = 0;
    for (int k = threadIdx.x; k < nblk; k += TPB_P) s += blkcnt[(size_t)k * NB + b];
    red[threadIdx.x] = s;
    __syncthreads();
    for (int off = TPB_P / 2; off > 0; off >>= 1) {
        if (threadIdx.x < off) red[threadIdx.x] += red[threadIdx.x + off];
        __syncthreads();
    }
    if (threadIdx.x == 0) totals[b] = red[0];
}

__global__ __launch_bounds__(TPB_P)
void s2_scan(const unsigned* __restrict__ totals, unsigned* __restrict__ base, int NB) {
    __shared__ unsigned t[TPB_P];
    int tid = threadIdx.x;
    unsigned v = (tid < NB) ? totals[tid] : 0u;
    t[tid] = v;
    __syncthreads();
    for (int off = 1; off < TPB_P; off <<= 1) {
        unsigned w = (tid >= off) ? t[tid - off] : 0u;
        __syncthreads();
        t[tid] += w;
        __syncthreads();
    }
    if (tid < NB) base[tid] = t[tid] - v;
    if (tid == NB - 1) base[NB] = t[tid];
}

__global__ __launch_bounds__(TPB_P)
void s3_start(const unsigned* __restrict__ blkcnt, const unsigned* __restrict__ base,
              unsigned* __restrict__ start, int NB, int nblk) {
    __shared__ unsigned t[TPB_P];
    int b = blockIdx.x;
    int tid = threadIdx.x;
    unsigned v = (tid < nblk) ? blkcnt[(size_t)tid * NB + b] : 0u;
    t[tid] = v;
    __syncthreads();
    for (int off = 1; off < TPB_P; off <<= 1) {
        unsigned w = (tid >= off) ? t[tid - off] : 0u;
        __syncthreads();
        t[tid] += w;
        __syncthreads();
    }
    if (tid < nblk) start[(size_t)tid * NB + b] = base[b] + t[tid] - v;
}

__global__ __launch_bounds__(TPB_P)
void p2_scatter(const int* __restrict__ src, const int* __restrict__ dst,
                const unsigned* __restrict__ start, unsigned* __restrict__ packed,
                int E, int chunk, int NB) {
    __shared__ unsigned stg[NBMAX * CAP];   // 64 KB staging
    __shared__ unsigned h[NBMAX];
    __shared__ unsigned gcur[NBMAX];
    int tid = threadIdx.x;
    int bid = blockIdx.x;
    for (int i = tid; i < NB; i += TPB_P) gcur[i] = start[(size_t)bid * NB + i];
    int beg = bid * chunk;
    int end = min(beg + chunk, E);
    int wid = tid >> 6, lane = tid & 63;
    for (int bb = beg; bb < end; bb += BATCH) {
        int bend = min(bb + BATCH, end);
        int n4 = (bend - bb) >> 2;          // batch multiple of 16
        for (int i = tid; i < NB; i += TPB_P) h[i] = 0u;
        __syncthreads();
        const uint32x4* s4 = (const uint32x4*)(src + bb);
        const uint32x4* d4 = (const uint32x4*)(dst + bb);
        for (int i = tid; i < n4; i += TPB_P) {
            uint32x4 s = __builtin_nontemporal_load(&s4[i]);
            uint32x4 d = __builtin_nontemporal_load(&d4[i]);
            unsigned sv[4] = {s.x, s.y, s.z, s.w};
            unsigned dv[4] = {d.x, d.y, d.z, d.w};
            #pragma unroll
            for (int k = 0; k < 4; ++k) {
                unsigned b = dv[k] >> BSH;
                unsigned val = (sv[k] << BSH) | (dv[k] & BMASK);
                unsigned pos = atomicAdd(&h[b], 1u);
                if (pos < CAP) stg[(b << 5) + ((pos + b) & 31u)] = val;  // bank-rotated
                else packed[gcur[b] + pos] = val;   // rare overflow
            }
        }
        __syncthreads();
        for (int b = wid; b < NB; b += TPB_P / 64) {
            unsigned cnt = h[b];
            unsigned n = cnt < CAP ? cnt : CAP;
            unsigned g0 = gcur[b];
            for (unsigned i = lane; i < n; i += 64)
                packed[g0 + i] = stg[(b << 5) + ((i + b) & 31u)];
            if (lane == 0) gcur[b] = g0 + cnt;
        }
        __syncthreads();
    }
}

// ---------------- e_pass_dual: both directions, XCD-partitioned ----------------
// DUAL grid: ((NB+3)/4)*8 slots. slot s -> XCD s%8 (round-robin heuristic).
// (s&7)<4: fwd bucket (s>>3)*4+(s&3); else rev bucket (s>>3)*4+((s&7)-4).
// XCDs 0-3 only touch x_f, XCDs 4-7 only x_r -> each 4MB array L2-resident.

template <bool FIRST, bool DUAL>
__global__ __launch_bounds__(TPB_E)
void e_pass_dual(const float* __restrict__ xf, const float* __restrict__ xr,
                 const unsigned* __restrict__ pf, const unsigned* __restrict__ pr,
                 const unsigned* __restrict__ basef, const unsigned* __restrict__ baser,
                 float* __restrict__ rcntf, float* __restrict__ rcntr,
                 float* __restrict__ outf, float* __restrict__ outr,
                 int N, int NB) {
    int bb, rev;
    if (DUAL) {
        int s = blockIdx.x;
        int r = s & 7;
        rev = (r >= 4) ? 1 : 0;
        bb = (s >> 3) * 4 + (r & 3);
        if (bb >= NB) return;                // whole block exits (uniform)
    } else {
        rev = 0;
        bb = blockIdx.x;
    }
    __shared__ float acc[BSZ];
    __shared__ unsigned c[FIRST ? BSZ : 1];
    int tid = threadIdx.x;
    for (int i = tid; i < BSZ; i += TPB_E) {
        acc[i] = 0.0f;
        if (FIRST) c[i] = 0u;
    }
    __syncthreads();
    const float* x = rev ? xr : xf;
    const unsigned* packed = rev ? pr : pf;
    const unsigned* boff = rev ? baser : basef;
    float* rcnt = rev ? rcntr : rcntf;
    float* outslice = rev ? outr : outf;

    int beg = (int)boff[bb], end = (int)boff[bb + 1];
    for (int e = beg + tid; e < end; e += TPB_E) {
        unsigned p = __builtin_nontemporal_load(&packed[e]);
        atomicAdd(&acc[p & BMASK], x[p >> BSH]);
        if (FIRST) atomicAdd(&c[p & BMASK], 1u);
    }
    __syncthreads();
    int nbase = bb << BSH;
    for (int i = tid; i < BSZ; i += TPB_E) {
        int node = nbase + i;
        if (node < N) {
            float rc;
            if (FIRST) {
                unsigned cv = c[i];
                rc = 1.0f / (float)(cv > 0u ? cv : 1u);
                rcnt[node] = rc;
            } else {
                rc = rcnt[node];
            }
            outslice[node] = acc[i] * rc;
        }
    }
}

// ---------------- fallback (global atomics) ----------------

#define TPB 256
#define MAX_BLOCKS 2048

__global__ void round_first(const float* __restrict__ x, const int* __restrict__ src,
                            const int* __restrict__ dst, float* __restrict__ agg,
                            float* __restrict__ cnt, int nE) {
    int i = blockIdx.x * blockDim.x + threadIdx.x;
    int stride = gridDim.x * blockDim.x;
    for (; i < nE; i += stride) {
        atomicAdd(&agg[dst[i]], x[src[i]]);
        atomicAdd(&cnt[dst[i]], 1.0f);
    }
}

__global__ void round_next(const float* __restrict__ x, const int* __restrict__ src,
                           const int* __restrict__ dst, float* __restrict__ agg, int nE) {
    int i = blockIdx.x * blockDim.x + threadIdx.x;
    int stride = gridDim.x * blockDim.x;
    for (; i < nE; i += stride) atomicAdd(&agg[dst[i]], x[src[i]]);
}

__global__ void normalize_k(float* __restrict__ out, const float* __restrict__ cnt, int n) {
    int i = blockIdx.x * blockDim.x + threadIdx.x;
    int stride = gridDim.x * blockDim.x;
    for (; i < n; i += stride) out[i] /= fmaxf(cnt[i], 1.0f);
}

// ---------------- launch ----------------

extern "C" void kernel_launch(void* const* d_in, const int* in_sizes, int n_in,
                              void* d_out, int out_size, void* d_ws, size_t ws_size,
                              hipStream_t stream) {
    const float* topic = (const float*)d_in[0];
    const int* ei  = (const int*)d_in[1];
    const int* rei = (const int*)d_in[2];
    const int N = in_sizes[0];
    const int E = in_sizes[1] / 2;

    float* out = (float*)d_out;   // 8 slices of N floats

    const int NB = (N + BSZ - 1) >> BSH;
    const int chunk = ((E + NPART * 16 - 1) / (NPART * 16)) * 16;

    size_t off = 0;
    auto alloc = [&](size_t bytes) { size_t o = off; off += (bytes + 255) & ~(size_t)255; return o; };
    size_t o_packed_f = alloc((size_t)E * 4);
    size_t o_rcnt_f   = alloc((size_t)N * 4);
    size_t o_rcnt_r   = alloc((size_t)N * 4);
    size_t o_blkcnt   = alloc((size_t)NPART * NB * 4);
    size_t o_start    = alloc((size_t)NPART * NB * 4);
    size_t o_totals   = alloc((size_t)NBMAX * 4);
    size_t o_base_f   = alloc((size_t)(NBMAX + 1) * 4);
    size_t o_base_r   = alloc((size_t)(NBMAX + 1) * 4);
    size_t need_seq   = off;
    size_t o_packed_r = alloc((size_t)E * 4);
    size_t need_dual  = off;

    bool shapes_ok = (NB >= 2) && (NB <= NBMAX) && (N <= (1 << 20)) &&
                     (E % 16 == 0) && (E > 0);
    bool dual = shapes_ok && (need_dual <= ws_size);
    bool seq  = shapes_ok && (need_seq <= ws_size);

    if (dual || seq) {
        char* ws = (char*)d_ws;
        unsigned* packed_f = (unsigned*)(ws + o_packed_f);
        unsigned* packed_r = dual ? (unsigned*)(ws + o_packed_r) : nullptr;
        float*    rcnt_f   = (float*)(ws + o_rcnt_f);
        float*    rcnt_r   = (float*)(ws + o_rcnt_r);
        unsigned* blkcnt   = (unsigned*)(ws + o_blkcnt);
        unsigned* start    = (unsigned*)(ws + o_start);
        unsigned* totals   = (unsigned*)(ws + o_totals);
        unsigned* base_f   = (unsigned*)(ws + o_base_f);
        unsigned* base_r   = (unsigned*)(ws + o_base_r);

        if (dual) {
            for (int dir = 0; dir < 2; ++dir) {
                const int* src = (dir == 0) ? ei : rei;
                const int* dst = src + E;
                unsigned* packed = (dir == 0) ? packed_f : packed_r;
                unsigned* base   = (dir == 0) ? base_f : base_r;
                p1_count<<<NPART, TPB_P, 0, stream>>>(dst, blkcnt, E, chunk, NB);
                s1_totals<<<NB, TPB_P, 0, stream>>>(blkcnt, totals, NB, NPART);
                s2_scan<<<1, TPB_P, 0, stream>>>(totals, base, NB);
                s3_start<<<NB, TPB_P, 0, stream>>>(blkcnt, base, start, NB, NPART);
                p2_scatter<<<NPART, TPB_P, 0, stream>>>(src, dst, start, packed, E, chunk, NB);
            }
            float* out_f = out;                      // slices 0..3
            float* out_r = out + (size_t)4 * N;      // slices 4..7
            const int grid_dual = ((NB + 3) / 4) * 8;
            e_pass_dual<true, true><<<grid_dual, TPB_E, 0, stream>>>(
                topic, topic, packed_f, packed_r, base_f, base_r,
                rcnt_f, rcnt_r, out_f, out_r, N, NB);
            for (int r = 1; r < 4; ++r) {
                e_pass_dual<false, true><<<grid_dual, TPB_E, 0, stream>>>(
                    out_f + (size_t)(r - 1) * N, out_r + (size_t)(r - 1) * N,
                    packed_f, packed_r, base_f, base_r,
                    rcnt_f, rcnt_r,
                    out_f + (size_t)r * N, out_r + (size_t)r * N, N, NB);
            }
        } else {
            for (int dir = 0; dir < 2; ++dir) {
                const int* src = (dir == 0) ? ei : rei;
                const int* dst = src + E;
                float* oslab = out + (size_t)dir * 4 * N;
                float* rcnt  = (dir == 0) ? rcnt_f : rcnt_r;
                unsigned* base = (dir == 0) ? base_f : base_r;
                p1_count<<<NPART, TPB_P, 0, stream>>>(dst, blkcnt, E, chunk, NB);
                s1_totals<<<NB, TPB_P, 0, stream>>>(blkcnt, totals, NB, NPART);
                s2_scan<<<1, TPB_P, 0, stream>>>(totals, base, NB);
                s3_start<<<NB, TPB_P, 0, stream>>>(blkcnt, base, start, NB, NPART);
                p2_scatter<<<NPART, TPB_P, 0, stream>>>(src, dst, start, packed_f, E, chunk, NB);
                e_pass_dual<true, false><<<NB, TPB_E, 0, stream>>>(
                    topic, topic, packed_f, packed_f, base, base,
                    rcnt, rcnt, oslab, oslab, N, NB);
                for (int r = 1; r < 4; ++r) {
                    e_pass_dual<false, false><<<NB, TPB_E, 0, stream>>>(
                        oslab + (size_t)(r - 1) * N, oslab + (size_t)(r - 1) * N,
                        packed_f, packed_f, base, base, rcnt, rcnt,
                        oslab + (size_t)r * N, oslab + (size_t)r * N, N, NB);
                }
            }
        }
        return;
    }

    // -------- fallback: global-atomic version --------
    const int* src = ei;
    const int* dst = ei + E;
    const int* rsrc = rei;
    const int* rdst = rei + E;

    float* cnt_f = (float*)d_ws;
    float* cnt_r = cnt_f + N;

    (void)hipMemsetAsync(d_out, 0, (size_t)out_size * sizeof(float), stream);
    (void)hipMemsetAsync(d_ws, 0, (size_t)2 * N * sizeof(float), stream);

    int eb = (E + TPB - 1) / TPB; if (eb > MAX_BLOCKS) eb = MAX_BLOCKS;
    int nb = (N + TPB - 1) / TPB; if (nb > MAX_BLOCKS) nb = MAX_BLOCKS;

    round_first<<<eb, TPB, 0, stream>>>(topic, src, dst, out, cnt_f, E);
    normalize_k<<<nb, TPB, 0, stream>>>(out, cnt_f, N);
    for (int r = 1; r < 4; ++r) {
        round_next<<<eb, TPB, 0, stream>>>(out + (size_t)(r - 1) * N, src, dst,
                                           out + (size_t)r * N, E);
        normalize_k<<<nb, TPB, 0, stream>>>(out + (size_t)r * N, cnt_f, N);
    }
    round_first<<<eb, TPB, 0, stream>>>(topic, rsrc, rdst, out + (size_t)4 * N, cnt_r, E);
    normalize_k<<<nb, TPB, 0, stream>>>(out + (size_t)4 * N, cnt_r, N);
    for (int r = 5; r < 8; ++r) {
        round_next<<<eb, TPB, 0, stream>>>(out + (size_t)(r - 1) * N, rsrc, rdst,
                                           out + (size_t)r * N, E);
        normalize_k<<<nb, TPB, 0, stream>>>(out + (size_t)r * N, cnt_r, N);
    }
}